// Round 1
// baseline (197.685 us; speedup 1.0000x reference)
//
#include <hip/hip_runtime.h>
#include <hip/hip_bf16.h>

// ---------------- problem constants ----------------
constexpr int Bc = 32, Sc = 4096, Ic = 64, Hc = 512, Oc = 64;
constexpr int Lc = 128;            // chunk length (timesteps per block)
constexpr int NCc = Sc / Lc;       // 32 chunks
constexpr int HSUB = 128;          // h-subtile width
constexpr int NSUB = Hc / HSUB;    // 4 subtiles

typedef __attribute__((ext_vector_type(8))) short short8;
typedef __attribute__((ext_vector_type(4))) short short4v;
typedef __attribute__((ext_vector_type(4))) float float4v;
typedef __attribute__((ext_vector_type(2))) unsigned uint2v;

__device__ __forceinline__ short f2bf(float f) {
    unsigned u = __builtin_bit_cast(unsigned, f);
    u += 0x7FFFu + ((u >> 16) & 1u);   // RNE
    return (short)(u >> 16);
}
__device__ __forceinline__ float bf2f(short s) {
    unsigned u = ((unsigned)(unsigned short)s) << 16;
    return __builtin_bit_cast(float, u);
}

// swizzled LDS byte offset: row-major tile, rowBytes stride, XOR-swizzle to kill
// the 16-way bank conflict on MFMA-fragment column reads (G4 rule).
__device__ __forceinline__ int swz(int row, int rowBytes, int byteInRow) {
    return row * rowBytes + (byteInRow ^ ((row & 7) << 4));
}

// ---------------- K0: transpose/convert weights ----------------
// bT[h][i] bf16 (512x64), cT[o][h] bf16 (64x512)
__global__ void prep_kernel(const float* __restrict__ bw, const float* __restrict__ cw,
                            short* __restrict__ bT, short* __restrict__ cT) {
    int gid = blockIdx.x * 256 + threadIdx.x;   // 65536 total
    if (gid < Ic * Hc) {
        int i = gid / Hc, h = gid % Hc;         // coalesced read over h
        bT[h * Ic + i] = f2bf(bw[gid]);
    } else {
        int idx = gid - Ic * Hc;                // c is [H][O]
        int h = idx / Oc, o = idx % Oc;
        cT[o * Hc + h] = f2bf(cw[idx]);
    }
}

// ---------------- K2: combine chunk carries ----------------
// true h at end of chunk k: Hk = last_k + A^L * H_{k-1}; carryIn[k] = H_{k-1}
__global__ void carry_kernel(const float* __restrict__ Adiag, const float* __restrict__ last,
                             float* __restrict__ carryIn) {
    int gid = blockIdx.x * 256 + threadIdx.x;   // 16384 = B*H
    int b = gid >> 9, h = gid & (Hc - 1);
    float a = Adiag[h];
    float aL = (a > 0.f) ? exp2f((float)Lc * log2f(a)) : 0.f;
    float run = 0.f;
    for (int k = 0; k < NCc; k++) {
        size_t idx = ((size_t)b * NCc + k) * Hc + h;
        carryIn[idx] = run;
        run = last[idx] + aL * run;
    }
}

// ---------------- K1/K3: per-chunk fused kernel ----------------
// WRITE_Y=0: compute local scan (zero init), emit chunk-final h only.
// WRITE_Y=1: scan seeded with carryIn, fused y = h @ c, write output.
template <int WRITE_Y>
__global__ __launch_bounds__(256, 2) void chunk_kernel(
    const float* __restrict__ x, const short* __restrict__ bT,
    const short* __restrict__ cT, const float* __restrict__ Adiag,
    const float* __restrict__ carryIn, float* __restrict__ lastOut,
    float* __restrict__ out) {
    __shared__ char Xs[128 * 128];    // [t][i]  bf16, swizzled, 16 KB
    __shared__ char bTs[128 * 128];   // [h][i]  bf16, swizzled, 16 KB (per subtile)
    __shared__ char cTs[64 * 256];    // [o][h]  bf16, swizzled, 16 KB (per subtile)
    __shared__ char xbh[128 * 256];   // [t][h]  bf16, swizzled, 32 KB (xb then h, in place)

    const int tid = threadIdx.x;
    const int chunk = blockIdx.x, b = blockIdx.y;
    const int t0 = chunk * Lc;
    const int l = tid & 63;
    const int tg = (tid >> 6) * 32;   // wave's 32-row t-slice of the 128-row tile

    // ---- stage X chunk -> LDS bf16 (coalesced float4 reads) ----
    const float4v* xg = (const float4v*)(x + ((size_t)b * Sc + t0) * Ic);
#pragma unroll
    for (int rr = 0; rr < 8; rr++) {
        int idx = rr * 256 + tid;               // 2048 float4 total
        float4v v = xg[idx];
        int row = idx >> 4, c4 = idx & 15;
        short4v sv;
        sv[0] = f2bf(v[0]); sv[1] = f2bf(v[1]); sv[2] = f2bf(v[2]); sv[3] = f2bf(v[3]);
        *(short4v*)(Xs + swz(row, 128, c4 * 8)) = sv;
    }

    float4v yacc[2][4];
    if (WRITE_Y) {
#pragma unroll
        for (int i = 0; i < 2; i++)
#pragma unroll
            for (int j = 0; j < 4; j++) yacc[i][j] = (float4v)0.f;
    }

    for (int hsu = 0; hsu < NSUB; hsu++) {
        __syncthreads();   // previous subtile fully consumed before overwriting tiles

        // ---- stage weight slices ----
        const uint2v* bg = (const uint2v*)(bT + hsu * HSUB * Ic);
#pragma unroll
        for (int rr = 0; rr < 8; rr++) {
            int idx = rr * 256 + tid;           // 2048 x 8B
            int row = idx >> 4, c8 = idx & 15;
            uint2v vv = bg[idx];
            *(uint2v*)(bTs + swz(row, 128, c8 * 8)) = vv;
        }
        if (WRITE_Y) {
            const uint2v* cg = (const uint2v*)cT;
#pragma unroll
            for (int rr = 0; rr < 8; rr++) {
                int idx = rr * 256 + tid;       // 2048 x 8B
                int row = idx >> 5, c8 = idx & 31;
                uint2v vv = cg[row * 128 + hsu * 32 + c8];
                *(uint2v*)(cTs + swz(row, 256, c8 * 8)) = vv;
            }
        }
        __syncthreads();

        // ---- xb = X @ b  (per wave: 32 t-rows x 128 h-cols, K=64) ----
        short8 afr[2][2];
#pragma unroll
        for (int ti = 0; ti < 2; ti++)
#pragma unroll
            for (int ks = 0; ks < 2; ks++) {
                int row = tg + ti * 16 + (l & 15);
                int byt = ks * 64 + ((l >> 4) * 16);
                afr[ti][ks] = *(const short8*)(Xs + swz(row, 128, byt));
            }
#pragma unroll
        for (int hj = 0; hj < 8; hj++) {
            short8 bfr[2];
#pragma unroll
            for (int ks = 0; ks < 2; ks++) {
                int row = hj * 16 + (l & 15);
                int byt = ks * 64 + ((l >> 4) * 16);
                bfr[ks] = *(const short8*)(bTs + swz(row, 128, byt));
            }
#pragma unroll
            for (int ti = 0; ti < 2; ti++) {
                float4v acc = (float4v)0.f;
                acc = __builtin_amdgcn_mfma_f32_16x16x32_bf16(afr[ti][0], bfr[0], acc, 0, 0, 0);
                acc = __builtin_amdgcn_mfma_f32_16x16x32_bf16(afr[ti][1], bfr[1], acc, 0, 0, 0);
                // D layout (HW-verified): row=(l>>4)*4+r, col=l&15
#pragma unroll
                for (int r = 0; r < 4; r++) {
                    int trow = tg + ti * 16 + (l >> 4) * 4 + r;
                    int hcol = hj * 16 + (l & 15);
                    *(short*)(xbh + swz(trow, 256, hcol * 2)) = f2bf(acc[r]);
                }
            }
        }
        __syncthreads();

        // ---- diagonal scan along t (thread j owns h-column j) ----
        if (tid < HSUB) {
            int h = hsu * HSUB + tid;
            float a = Adiag[h];
            float hstate = WRITE_Y ? carryIn[((size_t)b * NCc + chunk) * Hc + h] : 0.f;
#pragma unroll 4
            for (int t = 0; t < Lc; t++) {
                int off = swz(t, 256, tid * 2);
                float v = bf2f(*(short*)(xbh + off));
                hstate = fmaf(hstate, a, v);
                if (WRITE_Y) *(short*)(xbh + off) = f2bf(hstate);
            }
            if (!WRITE_Y) lastOut[((size_t)b * NCc + chunk) * Hc + h] = hstate;
        }
        __syncthreads();

        // ---- y += h @ c  (per wave: 32 t-rows x 64 o-cols, K=128) ----
        if (WRITE_Y) {
#pragma unroll
            for (int ks = 0; ks < 4; ks++) {
                short8 a2[2];
#pragma unroll
                for (int ti = 0; ti < 2; ti++) {
                    int row = tg + ti * 16 + (l & 15);
                    int byt = ks * 64 + ((l >> 4) * 16);
                    a2[ti] = *(const short8*)(xbh + swz(row, 256, byt));
                }
#pragma unroll
                for (int oj = 0; oj < 4; oj++) {
                    int row = oj * 16 + (l & 15);
                    int byt = ks * 64 + ((l >> 4) * 16);
                    short8 b2 = *(const short8*)(cTs + swz(row, 256, byt));
#pragma unroll
                    for (int ti = 0; ti < 2; ti++)
                        yacc[ti][oj] = __builtin_amdgcn_mfma_f32_16x16x32_bf16(a2[ti], b2, yacc[ti][oj], 0, 0, 0);
                }
            }
        }
    }

    // ---- write y tile ----
    if (WRITE_Y) {
        float* og = out + ((size_t)b * Sc + t0) * Oc;
#pragma unroll
        for (int ti = 0; ti < 2; ti++)
#pragma unroll
            for (int oj = 0; oj < 4; oj++)
#pragma unroll
                for (int r = 0; r < 4; r++) {
                    int t = tg + ti * 16 + (l >> 4) * 4 + r;
                    int o = oj * 16 + (l & 15);
                    og[t * Oc + o] = yacc[ti][oj][r];
                }
    }
}

// ---------------- host launch ----------------
extern "C" void kernel_launch(void* const* d_in, const int* in_sizes, int n_in,
                              void* d_out, int out_size, void* d_ws, size_t ws_size,
                              hipStream_t stream) {
    (void)in_sizes; (void)n_in; (void)out_size; (void)ws_size;
    const float* x     = (const float*)d_in[0];   // [B,S,I] f32
    const float* bw    = (const float*)d_in[1];   // [I,H]   f32
    const float* Adiag = (const float*)d_in[2];   // [H]     f32
    const float* cw    = (const float*)d_in[3];   // [H,O]   f32
    float* out = (float*)d_out;                   // [B,S*O] f32

    // workspace layout (4.3 MB total)
    float* last    = (float*)d_ws;                        // [B][NC][H] f32, 2 MB
    float* carryIn = last + (size_t)Bc * NCc * Hc;        // [B][NC][H] f32, 2 MB
    short* bT      = (short*)(carryIn + (size_t)Bc * NCc * Hc);  // [H][I] bf16, 64 KB
    short* cT      = bT + Ic * Hc;                        // [O][H] bf16, 64 KB

    prep_kernel<<<256, 256, 0, stream>>>(bw, cw, bT, cT);
    chunk_kernel<0><<<dim3(NCc, Bc), 256, 0, stream>>>(x, bT, cT, Adiag, nullptr, last, nullptr);
    carry_kernel<<<64, 256, 0, stream>>>(Adiag, last, carryIn);
    chunk_kernel<1><<<dim3(NCc, Bc), 256, 0, stream>>>(x, bT, cT, Adiag, carryIn, nullptr, out);
}